// Round 16
// baseline (211.120 us; speedup 1.0000x reference)
//
#include <hip/hip_runtime.h>
#include <hip/hip_cooperative_groups.h>

namespace cg = cooperative_groups;

typedef unsigned short u16;
typedef u16 u16x8 __attribute__((ext_vector_type(8)));
typedef __bf16 bf16x8 __attribute__((ext_vector_type(8)));
typedef float f32x4 __attribute__((ext_vector_type(4)));

#define MFMA16 __builtin_amdgcn_mfma_f32_16x16x32_bf16

__device__ __forceinline__ u16 f2bf(float f) {
  unsigned u = __builtin_bit_cast(unsigned, f);
  u += 0x7FFFu + ((u >> 16) & 1u);
  return (u16)(u >> 16);
}

// XOR-swizzled LDS byte address for 64-bf16 (128B) rows (guide G4).
__device__ __forceinline__ int swz(int row, int bcol) {
  return row * 128 + (bcol ^ ((row & 7) << 4));
}

__device__ __forceinline__ void gl16(const u16* g, u16* l) {
  __builtin_amdgcn_global_load_lds(
      (const __attribute__((address_space(1))) unsigned int*)g,
      (__attribute__((address_space(3))) unsigned int*)l, 16, 0, 0);
}

// raw workgroup barrier (no forced vmcnt(0) drain)
__device__ __forceinline__ void BARR() {
  asm volatile("" ::: "memory");
  __builtin_amdgcn_s_barrier();
  asm volatile("" ::: "memory");
}
#define VMCNT(n) asm volatile("s_waitcnt vmcnt(" #n ")" ::: "memory")
#define LGKM0 asm volatile("s_waitcnt lgkmcnt(0)" ::: "memory")

// ---------------------------------------------------------------------------
// 128x64-tile 2-phase counted-vmcnt GEMM core (r12/r13-proven).
//  ph1: STG B[t+1] (2 gl16) | dsr A(8)+B-n0(2) | 8 MFMA (m x n0) | bar
//  ph2: STG A[t+2] (4 gl16) | dsr B-n1(2)      | 8 MFMA (m x n1) | vmcnt(4) | bar
// A read ONLY in ph1 -> ph2's A[t+2] staging is 1 barrier past A's last read.
// Cross-tile reuse in a loop is safe: every next-tile prologue stage target
// is >=1 barrier past its last reader (audited r12).
// ---------------------------------------------------------------------------
#define ZSTGA(tt, j)                                                        \
  gl16(Ain + (m0 + (w << 5) + (j)*8 + (lane >> 3)) * 1024 + (tt)*64 +       \
           (((lane & 7) ^ (lane >> 3)) << 3),                               \
       (u16*)(sb + ((tt)&1) * 24576 + (w << 12) + ((j) << 10)))
#define ZSTGB(tt, j)                                                        \
  gl16(W + (n0 + (w << 4) + (j)*8 + (lane >> 3)) * 1024 + (tt)*64 +         \
           (((lane & 7) ^ (lane >> 3)) << 3),                               \
       (u16*)(sb + ((tt)&1) * 24576 + 16384 + (w << 11) + ((j) << 10)))
#define ZLDA()                                                              \
  _Pragma("unroll") for (int m = 0; m < 4; ++m) {                           \
    char* p = sb + bo + rowAb + m * 2048;                                   \
    af[0][m] = __builtin_bit_cast(bf16x8, *(const u16x8*)(p + colr0));      \
    af[1][m] = __builtin_bit_cast(bf16x8, *(const u16x8*)(p + colr1));      \
  }
#define ZLDB(n)                                                             \
  {                                                                         \
    char* p = sb + bo + rowBb + (n)*2048;                                   \
    bf[0][n] = __builtin_bit_cast(bf16x8, *(const u16x8*)(p + colr0));      \
    bf[1][n] = __builtin_bit_cast(bf16x8, *(const u16x8*)(p + colr1));      \
  }
#define ZFMA(n)                                                             \
  __builtin_amdgcn_s_setprio(1);                                            \
  _Pragma("unroll") for (int m = 0; m < 4; ++m) {                           \
    acc[m][n] = MFMA16(af[0][m], bf[0][n], acc[m][n], 0, 0, 0);             \
    acc[m][n] = MFMA16(af[1][m], bf[1][n], acc[m][n], 0, 0, 0);             \
  }                                                                         \
  __builtin_amdgcn_s_setprio(0);

__device__ __forceinline__ void core64(const u16* __restrict__ Ain,
                                       const u16* __restrict__ W, int m0,
                                       int n0, char* sb, f32x4 (&acc)[4][2]) {
  const int tid = threadIdx.x, lane = tid & 63, w = tid >> 6;
  const int wm = w >> 1, wn = w & 1;
  const int r = lane & 15, g = lane >> 4;
  bf16x8 af[2][4], bf[2][2];

  const int colr0 = (g * 16) ^ ((r & 7) << 4);
  const int colr1 = (64 + g * 16) ^ ((r & 7) << 4);
  const int rowAb = (wm * 64 + r) * 128;
  const int rowBb = 16384 + (wn * 32 + r) * 128;

  // prologue: A0(4), B0(2), A1(4); A1 stays in flight
#pragma unroll
  for (int j = 0; j < 4; ++j) ZSTGA(0, j);
#pragma unroll
  for (int j = 0; j < 2; ++j) ZSTGB(0, j);
#pragma unroll
  for (int j = 0; j < 4; ++j) ZSTGA(1, j);
  VMCNT(4);
  __builtin_amdgcn_s_barrier();
  asm volatile("" ::: "memory");

  for (int t = 0; t < 16; ++t) {
    const int bo = (t & 1) * 24576;
    if (t < 15) { ZSTGB(t + 1, 0); ZSTGB(t + 1, 1); }
    ZLDA();
    ZLDB(0);
    ZFMA(0);
    BARR();
    if (t < 14) { ZSTGA(t + 2, 0); ZSTGA(t + 2, 1); ZSTGA(t + 2, 2); ZSTGA(t + 2, 3); }
    ZLDB(1);
    ZFMA(1);
    if (t < 14) { VMCNT(4); } else if (t == 14) { VMCNT(0); }
    BARR();
  }
}

// ---------------------------------------------------------------------------
// Phase bodies (byte-identical math to r13's separate kernels)
// ---------------------------------------------------------------------------
__device__ void qkv_tile(int vt, const u16* __restrict__ ws, const float* c0,
                         const float* c1, const float* c2, u16* o0, u16* o1,
                         u16* o2, char* sb) {
  const int s = (vt & 7) * 192 + (vt >> 3);  // XCD swizzle, 1536 % 8 == 0
  const int z = s / 512;
  const int rem = s & 511;
  const int m0 = (rem >> 4) << 7;
  const int n0 = (rem & 15) << 6;

  const u16* __restrict__ Ain = ws + 4194304 + z * 4194304;
  const u16* __restrict__ W = ws + z * 1048576;
  const float* Bi = (z == 0) ? c0 : (z == 1) ? c1 : c2;
  u16* O = (z == 0) ? o0 : (z == 1) ? o1 : o2;

  const int tid = threadIdx.x, lane = tid & 63, w = tid >> 6;
  const int wm = w >> 1, wn = w & 1;
  const int r = lane & 15, g = lane >> 4;

  f32x4 acc[4][2] = {};
  core64(Ain, W, m0, n0, sb, acc);

#pragma unroll
  for (int n = 0; n < 2; ++n) {
    const int gn = n0 + wn * 32 + n * 16 + r;
    const int hh = gn >> 6, d = gn & 63;
    const float bv = Bi[gn];
#pragma unroll
    for (int m = 0; m < 4; ++m) {
#pragma unroll
      for (int q = 0; q < 4; ++q) {
        int gm = m0 + wm * 64 + m * 16 + g * 4 + q;
        int bb = gm >> 11, sIdx = gm & 2047;
        O[((bb * 16 + hh) * 2048 + sIdx) * 64 + d] = f2bf(acc[m][n][q] + bv);
      }
    }
  }
}

__device__ void out_tile(int vo, const u16* __restrict__ Ain,
                         const u16* __restrict__ W, const float* Bi, float* C,
                         char* sb) {
  const int s = (vo & 7) * 64 + (vo >> 3);  // XCD swizzle, 512 % 8 == 0
  const int m0 = (s >> 4) << 7;
  const int n0 = (s & 15) << 6;

  const int tid = threadIdx.x, lane = tid & 63, w = tid >> 6;
  const int wm = w >> 1, wn = w & 1;
  const int r = lane & 15, g = lane >> 4;

  f32x4 acc[4][2] = {};
  core64(Ain, W, m0, n0, sb, acc);

#pragma unroll
  for (int m = 0; m < 4; ++m) {
#pragma unroll
    for (int n = 0; n < 2; ++n) {
      int gn = n0 + wn * 32 + n * 16 + r;
      float bv = Bi[gn];
#pragma unroll
      for (int q = 0; q < 4; ++q) {
        int gm = m0 + wm * 64 + m * 16 + g * 4 + q;
        C[gm * 1024 + gn] = acc[m][n][q] + bv;
      }
    }
  }
}

__device__ void attn_vb(int vb, const u16* __restrict__ Q,
                        const u16* __restrict__ K, const u16* __restrict__ V,
                        u16* __restrict__ O, char* shp) {
  const int qt = vb & 31, h = (vb >> 5) & 15, b = vb >> 9;
  const int tid = threadIdx.x, lane = tid & 63, w = tid >> 6;
  const int r = lane & 15, g = lane >> 4;
  const int q0 = qt * 64;
  const int base = (b * 16 + h) * 131072;
  const u16* Qb = Q + base;

  u16* Ks = (u16*)shp;             // 2 x 4096 u16 (16 KB)
  u16* Vt = (u16*)(shp + 16384);   // 2 x 4096 u16 (16 KB)
  u16* Pl = (u16*)(shp + 32768);   // 4608 u16 (9 KB)

  bf16x8 qf[2];
  {
    const u16* qp = Qb + (q0 + w * 16 + r) * 64 + g * 8;
    qf[0] = __builtin_bit_cast(bf16x8, *(const u16x8*)qp);
    qf[1] = __builtin_bit_cast(bf16x8, *(const u16x8*)(qp + 32));
  }

  f32x4 acc[4] = {};
  float m_run[4] = {-1e30f, -1e30f, -1e30f, -1e30f};
  float l_run[4] = {};

  const int nt = (qt <= 3) ? (qt + 1) : 4;
  const int srow = tid >> 3, sc = (tid & 7) * 8;
  const u16* Kg = K + base + srow * 64 + sc;
  const u16* Vg = V + base + srow * 64 + sc;

  u16x8 krA[2], vrA[2], krB[2], vrB[2];
  krA[0] = *(const u16x8*)(Kg);
  krA[1] = *(const u16x8*)(Kg + 2048);
  vrA[0] = *(const u16x8*)(Vg);
  vrA[1] = *(const u16x8*)(Vg + 2048);

#pragma unroll
  for (int tix = 0; tix < 4; ++tix) {
    if (tix < nt) {
      const int j0 = ((tix == 0) ? 0 : ((qt <= 3) ? tix : (qt - 3 + tix))) * 64;
      const int bo = (tix & 1) * 8192;
      if ((tix & 1) == 0) {
#pragma unroll
        for (int i = 0; i < 2; ++i) {
          int row = i * 32 + srow;
          *(u16x8*)((char*)Ks + bo + swz(row, sc * 2)) = krA[i];
#pragma unroll
          for (int qq = 0; qq < 8; ++qq) {
            int d = sc + qq;
            *(u16*)((char*)Vt + bo + d * 128 + ((2 * row) ^ ((d & 7) << 4))) =
                vrA[i][qq];
          }
        }
      } else {
#pragma unroll
        for (int i = 0; i < 2; ++i) {
          int row = i * 32 + srow;
          *(u16x8*)((char*)Ks + bo + swz(row, sc * 2)) = krB[i];
#pragma unroll
          for (int qq = 0; qq < 8; ++qq) {
            int d = sc + qq;
            *(u16*)((char*)Vt + bo + d * 128 + ((2 * row) ^ ((d & 7) << 4))) =
                vrB[i][qq];
          }
        }
      }
      if (tix + 1 < nt) {
        const int jn = (((qt <= 3) ? (tix + 1) : (qt - 2 + tix)) * 64) * 64;
        if ((tix & 1) == 0) {
          krB[0] = *(const u16x8*)(Kg + jn);
          krB[1] = *(const u16x8*)(Kg + jn + 2048);
          vrB[0] = *(const u16x8*)(Vg + jn);
          vrB[1] = *(const u16x8*)(Vg + jn + 2048);
        } else {
          krA[0] = *(const u16x8*)(Kg + jn);
          krA[1] = *(const u16x8*)(Kg + jn + 2048);
          vrA[0] = *(const u16x8*)(Vg + jn);
          vrA[1] = *(const u16x8*)(Vg + jn + 2048);
        }
      }
      LGKM0;
      BARR();

      f32x4 S[4] = {};
#pragma unroll
      for (int kk = 0; kk < 2; ++kk)
#pragma unroll
        for (int n = 0; n < 4; ++n) {
          bf16x8 kf = __builtin_bit_cast(
              bf16x8, *(const u16x8*)((char*)Ks + bo +
                                      swz(n * 16 + r, kk * 64 + g * 16)));
          S[n] = MFMA16(qf[kk], kf, S[n], 0, 0, 0);
        }

      float mloc[4] = {-1e30f, -1e30f, -1e30f, -1e30f};
#pragma unroll
      for (int n = 0; n < 4; ++n) {
        int j = j0 + n * 16 + r;
#pragma unroll
        for (int q = 0; q < 4; ++q) {
          int i = q0 + w * 16 + g * 4 + q;
          bool ok = (j <= i) && (((i - j) <= 128) || (j < 16));
          float s = ok ? S[n][q] * 0.125f : -1e30f;
          S[n][q] = s;
          mloc[q] = fmaxf(mloc[q], s);
        }
      }
#pragma unroll
      for (int q = 0; q < 4; ++q)
#pragma unroll
        for (int off = 1; off < 16; off <<= 1)
          mloc[q] = fmaxf(mloc[q], __shfl_xor(mloc[q], off));

      float alpha[4], rsum[4] = {};
#pragma unroll
      for (int q = 0; q < 4; ++q) {
        float mn = fmaxf(m_run[q], mloc[q]);
        alpha[q] = __expf(m_run[q] - mn);
        m_run[q] = mn;
      }
#pragma unroll
      for (int n = 0; n < 4; ++n)
#pragma unroll
        for (int q = 0; q < 4; ++q) {
          float p = __expf(S[n][q] - m_run[q]);
          S[n][q] = p;
          rsum[q] += p;
        }
#pragma unroll
      for (int q = 0; q < 4; ++q) {
#pragma unroll
        for (int off = 1; off < 16; off <<= 1)
          rsum[q] += __shfl_xor(rsum[q], off);
        l_run[q] = l_run[q] * alpha[q] + rsum[q];
      }
#pragma unroll
      for (int n = 0; n < 4; ++n) {
        acc[n][0] *= alpha[0];
        acc[n][1] *= alpha[1];
        acc[n][2] *= alpha[2];
        acc[n][3] *= alpha[3];
      }

#pragma unroll
      for (int n = 0; n < 4; ++n)
#pragma unroll
        for (int q = 0; q < 4; ++q)
          *((u16*)((char*)Pl + w * 2304 + (g * 4 + q) * 144) + (n * 16 + r)) =
              f2bf(S[n][q]);

#pragma unroll
      for (int kk = 0; kk < 2; ++kk) {
        bf16x8 pf = __builtin_bit_cast(
            bf16x8, *(const u16x8*)((char*)Pl + w * 2304 + r * 144 + kk * 64 +
                                    g * 16));
#pragma unroll
        for (int n = 0; n < 4; ++n) {
          bf16x8 vf = __builtin_bit_cast(
              bf16x8, *(const u16x8*)((char*)Vt + bo +
                                      swz(n * 16 + r, kk * 64 + g * 16)));
          acc[n] = MFMA16(pf, vf, acc[n], 0, 0, 0);
        }
      }
    }
  }

#pragma unroll
  for (int n = 0; n < 4; ++n)
#pragma unroll
    for (int q = 0; q < 4; ++q) {
      int s = q0 + w * 16 + g * 4 + q;
      int d = n * 16 + r;
      O[(b * 2048 + s) * 1024 + h * 64 + d] = f2bf(acc[n][q] / l_run[q]);
    }
  // WAR fence: next virtual block's staging vs this one's in-flight LDS reads
  BARR();
}

// ---------------------------------------------------------------------------
// Fused cooperative kernel: cast -> [grid.sync] -> qkv -> [grid.sync] ->
// attn -> [grid.sync] -> out. Grid-stride everywhere; grid sized by the
// occupancy query so all blocks are co-resident.
// ws (u16): Wq 0 | Wk 1M | Wv 2M | Wo 3M | Xq 4M | Xk 8M | Xv 12M |
//           Qw 16M | Kw 20M | Vw 24M | Aw aliases Xq (4M)
// ---------------------------------------------------------------------------
__global__ __launch_bounds__(256)
void fused_all(const float* __restrict__ q, const float* __restrict__ k,
               const float* __restrict__ v, const float* __restrict__ wq,
               const float* __restrict__ wk, const float* __restrict__ wv,
               const float* __restrict__ wo, const float* __restrict__ bq,
               const float* __restrict__ bk, const float* __restrict__ bv,
               const float* __restrict__ bo_, u16* __restrict__ ws,
               float* __restrict__ outp) {
  __shared__ char SH[49152];  // 48 KB shared pool for all phases
  cg::grid_group grid = cg::this_grid();
  const int bid = blockIdx.x, tid = threadIdx.x;

  // ---- phase 1: fp32 -> bf16 cast (16M u16 elements)
  for (long i = ((long)bid * 256 + tid) * 8; i < 16777216;
       i += (long)gridDim.x * 2048) {
    const float* s;
    u16* d;
    if (i < 12582912) {
      const int seg = (int)(i >> 22);
      const float* xs = (seg == 0) ? q : (seg == 1) ? k : v;
      s = xs + (i & 4194303);
      d = ws + 4194304 + i;
    } else {
      const long j = i - 12582912;
      const int seg = (int)(j >> 20);
      const float* wsrc =
          (seg == 0) ? wq : (seg == 1) ? wk : (seg == 2) ? wv : wo;
      s = wsrc + (j & 1048575);
      d = ws + j;
    }
    float4 v0 = *(const float4*)s;
    float4 v1 = *(const float4*)(s + 4);
    u16x8 p = {f2bf(v0.x), f2bf(v0.y), f2bf(v0.z), f2bf(v0.w),
               f2bf(v1.x), f2bf(v1.y), f2bf(v1.z), f2bf(v1.w)};
    *(u16x8*)d = p;
  }
  grid.sync();

  // ---- phase 2: qkv projection (1536 virtual tiles)
  u16* Qw = ws + 16777216;
  u16* Kw = ws + 20971520;
  u16* Vw = ws + 25165824;
  for (int vt = bid; vt < 1536; vt += gridDim.x)
    qkv_tile(vt, ws, bq, bk, bv, Qw, Kw, Vw, SH);
  grid.sync();

  // ---- phase 3: sparse flash attention (1024 virtual blocks)
  u16* Aw = ws + 4194304;  // aliases Xq (dead after qkv)
  for (int vb = bid; vb < 1024; vb += gridDim.x)
    attn_vb(vb, Qw, Kw, Vw, Aw, SH);
  grid.sync();

  // ---- phase 4: output projection (512 virtual tiles)
  for (int vo = bid; vo < 512; vo += gridDim.x)
    out_tile(vo, Aw, ws + 3145728, bo_, outp, SH);
}

// ---------------------------------------------------------------------------
extern "C" void kernel_launch(void* const* d_in, const int* in_sizes, int n_in,
                              void* d_out, int out_size, void* d_ws,
                              size_t ws_size, hipStream_t stream) {
  const float* q = (const float*)d_in[0];
  const float* k = (const float*)d_in[1];
  const float* v = (const float*)d_in[2];
  const float* wq = (const float*)d_in[3];
  const float* bq = (const float*)d_in[4];
  const float* wk = (const float*)d_in[5];
  const float* bk = (const float*)d_in[6];
  const float* wv = (const float*)d_in[7];
  const float* bv = (const float*)d_in[8];
  const float* wo = (const float*)d_in[9];
  const float* bo_ = (const float*)d_in[10];
  u16* ws = (u16*)d_ws;
  float* outp = (float*)d_out;

  int maxB = 0;
  hipOccupancyMaxActiveBlocksPerMultiprocessor(&maxB, fused_all, 256, 0);
  if (maxB < 1) maxB = 1;
  if (maxB > 3) maxB = 3;
  const int grid = 256 * maxB;  // 256 CUs on MI355X; all blocks co-resident

  void* args[] = {&q,  &k,  &v,  &wq, &wk, &wv,  &wo,
                  &bq, &bk, &bv, &bo_, &ws, &outp};
  hipLaunchCooperativeKernel(fused_all, dim3(grid), dim3(256), args, 0,
                             stream);
}

// Round 17
// 109.079 us; speedup vs baseline: 1.9355x; 1.9355x over previous
//
#include <hip/hip_runtime.h>

typedef unsigned short u16;
typedef u16 u16x8 __attribute__((ext_vector_type(8)));
typedef __bf16 bf16x8 __attribute__((ext_vector_type(8)));
typedef float f32x4 __attribute__((ext_vector_type(4)));

#define MFMA16 __builtin_amdgcn_mfma_f32_16x16x32_bf16

__device__ __forceinline__ u16 f2bf(float f) {
  unsigned u = __builtin_bit_cast(unsigned, f);
  u += 0x7FFFu + ((u >> 16) & 1u);
  return (u16)(u >> 16);
}

__device__ __forceinline__ bf16x8 cvt8(float4 a, float4 b) {
  return (bf16x8){(__bf16)a.x, (__bf16)a.y, (__bf16)a.z, (__bf16)a.w,
                  (__bf16)b.x, (__bf16)b.y, (__bf16)b.z, (__bf16)b.w};
}

// XOR-swizzled LDS byte address for 64-bf16 (128B) rows (guide G4).
__device__ __forceinline__ int swz(int row, int bcol) {
  return row * 128 + (bcol ^ ((row & 7) << 4));
}

__device__ __forceinline__ void gl16(const u16* g, u16* l) {
  __builtin_amdgcn_global_load_lds(
      (const __attribute__((address_space(1))) unsigned int*)g,
      (__attribute__((address_space(3))) unsigned int*)l, 16, 0, 0);
}

// raw workgroup barrier (no forced vmcnt(0) drain)
__device__ __forceinline__ void BARR() {
  asm volatile("" ::: "memory");
  __builtin_amdgcn_s_barrier();
  asm volatile("" ::: "memory");
}
#define VMCNT(n) asm volatile("s_waitcnt vmcnt(" #n ")" ::: "memory")
#define LGKM0 asm volatile("s_waitcnt lgkmcnt(0)" ::: "memory")

// ---------------------------------------------------------------------------
// fp32 -> bf16 cast, WEIGHTS ONLY. 4M elems, 8/thread, 2048 blocks.
// ws (u16): Wq 0 | Wk 1M | Wv 2M | Wo 3M | Qw 4M | Kw 8M | Vw 12M | Aw 16M
// ---------------------------------------------------------------------------
__global__ __launch_bounds__(256)
void cast_w(const float* __restrict__ wq, const float* __restrict__ wk,
            const float* __restrict__ wv, const float* __restrict__ wo,
            u16* __restrict__ ws) {
  const int i = (blockIdx.x * 256 + threadIdx.x) * 8;
  const int seg = i >> 20;
  const float* s =
      ((seg == 0) ? wq : (seg == 1) ? wk : (seg == 2) ? wv : wo) + (i & 1048575);
  float4 v0 = *(const float4*)s;
  float4 v1 = *(const float4*)(s + 4);
  u16x8 p = {f2bf(v0.x), f2bf(v0.y), f2bf(v0.z), f2bf(v0.w),
             f2bf(v1.x), f2bf(v1.y), f2bf(v1.z), f2bf(v1.w)};
  *(u16x8*)(ws + i) = p;
}

// ---------------------------------------------------------------------------
// QKV projection, fp32-A direct, corrected swizzle. 128x64 tile, 1536 blocks,
// 4 waves (2m x 2n), LDS 80 KB (2 blocks/CU):
//   A[buf] fp32 128x64 = 32 KB at buf*32768 ; B[buf] bf16 at 65536+buf*8192.
// A store (per wave, 8 chunks of 4 rows): chunk(w,j) row = w*32+4j+g;
//   source col16 = r ^ ((4j+g)&15)  [j compile-time -> per-j constant XOR];
//   linear LDS dest (rule 21). Read of row R (R&15=r): col16 c at slot c^r
//   -> byte ((c^r)<<4). 64-lane b128 spreads 8 lanes/bank-quad (uniform).
// Phases identical to r13 core64 ledger (A read ONLY in ph1):
//  ph1: STG B[t+1](2) | A frags (16 dsr fp32 + cvt) + B-n0(2) | 8 MFMA | bar
//  ph2: STG A[t+2](8) | B-n1(2) | 8 MFMA | vmcnt(8) | bar
// vmcnt(8): leaves A[t+2](8) in flight; retires A[t+1]+B[t+1].
// Prologue: A0(8),B0(2),A1(8) -> vmcnt(8). Tail: t=14 -> vmcnt(0).
// ---------------------------------------------------------------------------
#define FSTGA(tt, j)                                                        \
  gl16((const u16*)(X + (m0 + (w << 5) + 4 * (j) + g) * 1024 + (tt)*64 +    \
                    ((r ^ ((4 * (j) + g) & 15)) << 2)),                     \
       (u16*)(sb + (((tt)&1) << 15) + (((w << 3) + (j)) << 10)))
#define FSTGB(tt, j)                                                        \
  gl16(W + (n0 + (w << 4) + (j)*8 + (lane >> 3)) * 1024 + (tt)*64 +         \
           (((lane & 7) ^ (lane >> 3)) << 3),                               \
       (u16*)(sb + 65536 + (((tt)&1) << 13) + (w << 11) + ((j) << 10)))
#define FLDA()                                                              \
  _Pragma("unroll") for (int m = 0; m < 4; ++m) {                           \
    const char* p = sb + boA + rowAf + m * 4096;                            \
    float4 x0 = *(const float4*)(p + (((2 * g + 0) ^ r) << 4));             \
    float4 x1 = *(const float4*)(p + (((2 * g + 1) ^ r) << 4));             \
    float4 x2 = *(const float4*)(p + (((2 * g + 8) ^ r) << 4));             \
    float4 x3 = *(const float4*)(p + (((2 * g + 9) ^ r) << 4));             \
    af[0][m] = cvt8(x0, x1);                                                \
    af[1][m] = cvt8(x2, x3);                                                \
  }
#define FLDB(n)                                                             \
  {                                                                         \
    const char* p = sb + 65536 + boB + rowBf + (n)*2048;                    \
    bf[0][n] = __builtin_bit_cast(bf16x8, *(const u16x8*)(p + colr0));      \
    bf[1][n] = __builtin_bit_cast(bf16x8, *(const u16x8*)(p + colr1));      \
  }
#define FFMA(n)                                                             \
  __builtin_amdgcn_s_setprio(1);                                            \
  _Pragma("unroll") for (int m = 0; m < 4; ++m) {                           \
    acc[m][n] = MFMA16(af[0][m], bf[0][n], acc[m][n], 0, 0, 0);             \
    acc[m][n] = MFMA16(af[1][m], bf[1][n], acc[m][n], 0, 0, 0);             \
  }                                                                         \
  __builtin_amdgcn_s_setprio(0);

__global__ __launch_bounds__(256)
void qkv_f32v2(const float* __restrict__ Xq, const float* __restrict__ Xk,
               const float* __restrict__ Xv, const u16* __restrict__ Wall,
               const float* __restrict__ bq, const float* __restrict__ bk,
               const float* __restrict__ bv, u16* __restrict__ Qw,
               u16* __restrict__ Kw, u16* __restrict__ Vw) {
  const int bid = blockIdx.x;
  const int s = (bid & 7) * 192 + (bid >> 3);  // XCD swizzle, 1536 % 8 == 0
  const int z = s / 512;
  const int rem = s & 511;
  const int m0 = (rem >> 4) << 7;  // 32 m-tiles of 128
  const int n0 = (rem & 15) << 6;  // 16 n-tiles of 64

  const float* __restrict__ X = (z == 0) ? Xq : (z == 1) ? Xk : Xv;
  const u16* __restrict__ W = Wall + z * 1048576;
  const float* Bi = (z == 0) ? bq : (z == 1) ? bk : bv;
  u16* O = (z == 0) ? Qw : (z == 1) ? Kw : Vw;

  const int tid = threadIdx.x, lane = tid & 63, w = tid >> 6;
  const int wm = w >> 1, wn = w & 1;
  const int r = lane & 15, g = lane >> 4;

  __shared__ u16 SH[40960];  // 80 KB
  char* sb = (char*)SH;

  f32x4 acc[4][2] = {};
  bf16x8 af[2][4], bf[2][2];

  const int rowAf = (wm * 64 + r) * 256;  // fp32 row = 256B
  const int rowBf = (wn * 32 + r) * 128;
  const int colr0 = (g * 16) ^ ((r & 7) << 4);
  const int colr1 = (64 + g * 16) ^ ((r & 7) << 4);

  // prologue: A0(8), B0(2), A1(8); vmcnt(8) retires A0+B0, A1 in flight
#pragma unroll
  for (int j = 0; j < 8; ++j) FSTGA(0, j);
  FSTGB(0, 0);
  FSTGB(0, 1);
#pragma unroll
  for (int j = 0; j < 8; ++j) FSTGA(1, j);
  VMCNT(8);
  __builtin_amdgcn_s_barrier();
  asm volatile("" ::: "memory");

  for (int t = 0; t < 16; ++t) {
    const int boA = (t & 1) << 15;
    const int boB = (t & 1) << 13;
    // ---- phase 1: all A (fp32 + cvt) + B-n0
    if (t < 15) { FSTGB(t + 1, 0); FSTGB(t + 1, 1); }
    FLDA();
    FLDB(0);
    FFMA(0);
    BARR();
    // ---- phase 2: B-n1 only (A region not read -> A[t+2] staging safe)
    if (t < 14) {
#pragma unroll
      for (int j = 0; j < 8; ++j) FSTGA(t + 2, j);
    }
    FLDB(1);
    FFMA(1);
    if (t < 14) { VMCNT(8); } else if (t == 14) { VMCNT(0); }
    BARR();
  }

  // epilogue -> bf16 [B,H,S,64]; C/D layout col=lane&15, row=g*4+q
#pragma unroll
  for (int n = 0; n < 2; ++n) {
    const int gn = n0 + wn * 32 + n * 16 + r;
    const int hh = gn >> 6, d = gn & 63;
    const float bv = Bi[gn];
#pragma unroll
    for (int m = 0; m < 4; ++m) {
#pragma unroll
      for (int q = 0; q < 4; ++q) {
        int gm = m0 + wm * 64 + m * 16 + g * 4 + q;
        int bb = gm >> 11, sIdx = gm & 2047;
        O[((bb * 16 + hh) * 2048 + sIdx) * 64 + d] = f2bf(acc[m][n][q] + bv);
      }
    }
  }
}

// ---------------------------------------------------------------------------
// Shared 128x64-tile 2-phase counted-vmcnt GEMM core (r12-proven) — out proj.
// ---------------------------------------------------------------------------
#define ZSTGA(tt, j)                                                        \
  gl16(Ain + (m0 + (w << 5) + (j)*8 + (lane >> 3)) * 1024 + (tt)*64 +       \
           (((lane & 7) ^ (lane >> 3)) << 3),                               \
       (u16*)(sb + ((tt)&1) * 24576 + (w << 12) + ((j) << 10)))
#define ZSTGB(tt, j)                                                        \
  gl16(W + (n0 + (w << 4) + (j)*8 + (lane >> 3)) * 1024 + (tt)*64 +         \
           (((lane & 7) ^ (lane >> 3)) << 3),                               \
       (u16*)(sb + ((tt)&1) * 24576 + 16384 + (w << 11) + ((j) << 10)))
#define ZLDA()                                                              \
  _Pragma("unroll") for (int m = 0; m < 4; ++m) {                           \
    char* p = sb + bo + rowAb + m * 2048;                                   \
    af[0][m] = __builtin_bit_cast(bf16x8, *(const u16x8*)(p + colr0));      \
    af[1][m] = __builtin_bit_cast(bf16x8, *(const u16x8*)(p + colr1));      \
  }
#define ZLDB(n)                                                             \
  {                                                                         \
    char* p = sb + bo + rowBb + (n)*2048;                                   \
    bf[0][n] = __builtin_bit_cast(bf16x8, *(const u16x8*)(p + colr0));      \
    bf[1][n] = __builtin_bit_cast(bf16x8, *(const u16x8*)(p + colr1));      \
  }
#define ZFMA(n)                                                             \
  __builtin_amdgcn_s_setprio(1);                                            \
  _Pragma("unroll") for (int m = 0; m < 4; ++m) {                           \
    acc[m][n] = MFMA16(af[0][m], bf[0][n], acc[m][n], 0, 0, 0);             \
    acc[m][n] = MFMA16(af[1][m], bf[1][n], acc[m][n], 0, 0, 0);             \
  }                                                                         \
  __builtin_amdgcn_s_setprio(0);

__device__ __forceinline__ void core64(const u16* __restrict__ Ain,
                                       const u16* __restrict__ W, int m0,
                                       int n0, char* sb, f32x4 (&acc)[4][2]) {
  const int tid = threadIdx.x, lane = tid & 63, w = tid >> 6;
  const int wm = w >> 1, wn = w & 1;
  const int r = lane & 15, g = lane >> 4;
  bf16x8 af[2][4], bf[2][2];

  const int colr0 = (g * 16) ^ ((r & 7) << 4);
  const int colr1 = (64 + g * 16) ^ ((r & 7) << 4);
  const int rowAb = (wm * 64 + r) * 128;
  const int rowBb = 16384 + (wn * 32 + r) * 128;

#pragma unroll
  for (int j = 0; j < 4; ++j) ZSTGA(0, j);
#pragma unroll
  for (int j = 0; j < 2; ++j) ZSTGB(0, j);
#pragma unroll
  for (int j = 0; j < 4; ++j) ZSTGA(1, j);
  VMCNT(4);
  __builtin_amdgcn_s_barrier();
  asm volatile("" ::: "memory");

  for (int t = 0; t < 16; ++t) {
    const int bo = (t & 1) * 24576;
    if (t < 15) { ZSTGB(t + 1, 0); ZSTGB(t + 1, 1); }
    ZLDA();
    ZLDB(0);
    ZFMA(0);
    BARR();
    if (t < 14) { ZSTGA(t + 2, 0); ZSTGA(t + 2, 1); ZSTGA(t + 2, 2); ZSTGA(t + 2, 3); }
    ZLDB(1);
    ZFMA(1);
    if (t < 14) { VMCNT(4); } else if (t == 14) { VMCNT(0); }
    BARR();
  }
}

__global__ __launch_bounds__(256)
void out_gemm64(const u16* __restrict__ Ain, const u16* __restrict__ W,
                const float* __restrict__ Bi, float* __restrict__ C) {
  const int bid = blockIdx.x;
  const int s = (bid & 7) * 64 + (bid >> 3);  // XCD swizzle, 512 % 8 == 0
  const int m0 = (s >> 4) << 7;
  const int n0 = (s & 15) << 6;

  const int tid = threadIdx.x, lane = tid & 63, w = tid >> 6;
  const int wm = w >> 1, wn = w & 1;
  const int r = lane & 15, g = lane >> 4;

  __shared__ u16 SH[24576];  // 48 KB
  f32x4 acc[4][2] = {};
  core64(Ain, W, m0, n0, (char*)SH, acc);

#pragma unroll
  for (int m = 0; m < 4; ++m) {
#pragma unroll
    for (int n = 0; n < 2; ++n) {
      int gn = n0 + wn * 32 + n * 16 + r;
      float bv = Bi[gn];
#pragma unroll
      for (int q = 0; q < 4; ++q) {
        int gm = m0 + wm * 64 + m * 16 + g * 4 + q;
        C[gm * 1024 + gn] = acc[m][n][q] + bv;
      }
    }
  }
}

// ---------------------------------------------------------------------------
// Sparse flash attention (r8 version, T14 async-stage + dbuf K/V).
// grid (32 qtiles, 16 heads, 2 batch), 256 threads (4 waves x 16 q-rows).
// ---------------------------------------------------------------------------
__global__ __launch_bounds__(256)
void attn_kernel(const u16* __restrict__ Q, const u16* __restrict__ K,
                 const u16* __restrict__ V, u16* __restrict__ O) {
  const int qt = blockIdx.x, h = blockIdx.y, b = blockIdx.z;
  const int tid = threadIdx.x, lane = tid & 63, w = tid >> 6;
  const int r = lane & 15, g = lane >> 4;
  const int q0 = qt * 64;
  const int base = (b * 16 + h) * 131072;
  const u16* Qb = Q + base;

  __shared__ u16 Ks[2][4096];
  __shared__ u16 Vt[2][4096];  // transposed: Vt[d][j]
  __shared__ u16 Pl[4608];     // 4 waves x 16 rows x 144B stride

  bf16x8 qf[2];
  {
    const u16* qp = Qb + (q0 + w * 16 + r) * 64 + g * 8;
    qf[0] = __builtin_bit_cast(bf16x8, *(const u16x8*)qp);
    qf[1] = __builtin_bit_cast(bf16x8, *(const u16x8*)(qp + 32));
  }

  f32x4 acc[4] = {};
  float m_run[4] = {-1e30f, -1e30f, -1e30f, -1e30f};
  float l_run[4] = {};

  const int nt = (qt <= 3) ? (qt + 1) : 4;
  const int srow = tid >> 3, sc = (tid & 7) * 8;
  const u16* Kg = K + base + srow * 64 + sc;
  const u16* Vg = V + base + srow * 64 + sc;

  u16x8 krA[2], vrA[2], krB[2], vrB[2];
  krA[0] = *(const u16x8*)(Kg);
  krA[1] = *(const u16x8*)(Kg + 2048);
  vrA[0] = *(const u16x8*)(Vg);
  vrA[1] = *(const u16x8*)(Vg + 2048);

#pragma unroll
  for (int tix = 0; tix < 4; ++tix) {
    if (tix < nt) {
      const int j0 = ((tix == 0) ? 0 : ((qt <= 3) ? tix : (qt - 3 + tix))) * 64;
      const int bo = (tix & 1) * 8192;
      if ((tix & 1) == 0) {
#pragma unroll
        for (int i = 0; i < 2; ++i) {
          int row = i * 32 + srow;
          *(u16x8*)((char*)Ks + bo + swz(row, sc * 2)) = krA[i];
#pragma unroll
          for (int qq = 0; qq < 8; ++qq) {
            int d = sc + qq;
            *(u16*)((char*)Vt + bo + d * 128 + ((2 * row) ^ ((d & 7) << 4))) =
                vrA[i][qq];
          }
        }
      } else {
#pragma unroll
        for (int i = 0; i < 2; ++i) {
          int row = i * 32 + srow;
          *(u16x8*)((char*)Ks + bo + swz(row, sc * 2)) = krB[i];
#pragma unroll
          for (int qq = 0; qq < 8; ++qq) {
            int d = sc + qq;
            *(u16*)((char*)Vt + bo + d * 128 + ((2 * row) ^ ((d & 7) << 4))) =
                vrB[i][qq];
          }
        }
      }
      if (tix + 1 < nt) {
        const int jn = (((qt <= 3) ? (tix + 1) : (qt - 2 + tix)) * 64) * 64;
        if ((tix & 1) == 0) {
          krB[0] = *(const u16x8*)(Kg + jn);
          krB[1] = *(const u16x8*)(Kg + jn + 2048);
          vrB[0] = *(const u16x8*)(Vg + jn);
          vrB[1] = *(const u16x8*)(Vg + jn + 2048);
        } else {
          krA[0] = *(const u16x8*)(Kg + jn);
          krA[1] = *(const u16x8*)(Kg + jn + 2048);
          vrA[0] = *(const u16x8*)(Vg + jn);
          vrA[1] = *(const u16x8*)(Vg + jn + 2048);
        }
      }
      LGKM0;
      BARR();

      f32x4 S[4] = {};
#pragma unroll
      for (int kk = 0; kk < 2; ++kk)
#pragma unroll
        for (int n = 0; n < 4; ++n) {
          bf16x8 kf = __builtin_bit_cast(
              bf16x8, *(const u16x8*)((char*)Ks + bo +
                                      swz(n * 16 + r, kk * 64 + g * 16)));
          S[n] = MFMA16(qf[kk], kf, S[n], 0, 0, 0);
        }

      float mloc[4] = {-1e30f, -1e30f, -1e30f, -1e30f};
#pragma unroll
      for (int n = 0; n < 4; ++n) {
        int j = j0 + n * 16 + r;
#pragma unroll
        for (int q = 0; q < 4; ++q) {
          int i = q0 + w * 16 + g * 4 + q;
          bool ok = (j <= i) && (((i - j) <= 128) || (j < 16));
          float s = ok ? S[n][q] * 0.125f : -1e30f;
          S[n][q] = s;
          mloc[q] = fmaxf(mloc[q], s);
        }
      }
#pragma unroll
      for (int q = 0; q < 4; ++q)
#pragma unroll
        for (int off = 1; off < 16; off <<= 1)
          mloc[q] = fmaxf(mloc[q], __shfl_xor(mloc[q], off));

      float alpha[4], rsum[4] = {};
#pragma unroll
      for (int q = 0; q < 4; ++q) {
        float mn = fmaxf(m_run[q], mloc[q]);
        alpha[q] = __expf(m_run[q] - mn);
        m_run[q] = mn;
      }
#pragma unroll
      for (int n = 0; n < 4; ++n)
#pragma unroll
        for (int q = 0; q < 4; ++q) {
          float p = __expf(S[n][q] - m_run[q]);
          S[n][q] = p;
          rsum[q] += p;
        }
#pragma unroll
      for (int q = 0; q < 4; ++q) {
#pragma unroll
        for (int off = 1; off < 16; off <<= 1)
          rsum[q] += __shfl_xor(rsum[q], off);
        l_run[q] = l_run[q] * alpha[q] + rsum[q];
      }
#pragma unroll
      for (int n = 0; n < 4; ++n) {
        acc[n][0] *= alpha[0];
        acc[n][1] *= alpha[1];
        acc[n][2] *= alpha[2];
        acc[n][3] *= alpha[3];
      }

#pragma unroll
      for (int n = 0; n < 4; ++n)
#pragma unroll
        for (int q = 0; q < 4; ++q)
          *((u16*)((char*)Pl + w * 2304 + (g * 4 + q) * 144) + (n * 16 + r)) =
              f2bf(S[n][q]);

#pragma unroll
      for (int kk = 0; kk < 2; ++kk) {
        bf16x8 pf = __builtin_bit_cast(
            bf16x8, *(const u16x8*)((char*)Pl + w * 2304 + r * 144 + kk * 64 +
                                    g * 16));
#pragma unroll
        for (int n = 0; n < 4; ++n) {
          bf16x8 vf = __builtin_bit_cast(
              bf16x8, *(const u16x8*)((char*)Vt + bo +
                                      swz(n * 16 + r, kk * 64 + g * 16)));
          acc[n] = MFMA16(pf, vf, acc[n], 0, 0, 0);
        }
      }
    }
  }

#pragma unroll
  for (int n = 0; n < 4; ++n)
#pragma unroll
    for (int q = 0; q < 4; ++q) {
      int s = q0 + w * 16 + g * 4 + q;
      int d = n * 16 + r;
      O[(b * 2048 + s) * 1024 + h * 64 + d] = f2bf(acc[n][q] / l_run[q]);
    }
}

// ---------------------------------------------------------------------------
extern "C" void kernel_launch(void* const* d_in, const int* in_sizes, int n_in,
                              void* d_out, int out_size, void* d_ws,
                              size_t ws_size, hipStream_t stream) {
  const float* query = (const float*)d_in[0];
  const float* key = (const float*)d_in[1];
  const float* value = (const float*)d_in[2];
  const float* b_q = (const float*)d_in[4];
  const float* b_k = (const float*)d_in[6];
  const float* b_v = (const float*)d_in[8];
  const float* b_o = (const float*)d_in[10];

  u16* ws = (u16*)d_ws;
  // ws (u16): Wq 0 | Wk 1M | Wv 2M | Wo 3M | Qw 4M | Kw 8M | Vw 12M | Aw 16M
  u16* Qw = ws + 4194304;
  u16* Kw = ws + 8388608;
  u16* Vw = ws + 12582912;
  u16* Aw = ws + 16777216;

  cast_w<<<dim3(2048), dim3(256), 0, stream>>>(
      (const float*)d_in[3], (const float*)d_in[5], (const float*)d_in[7],
      (const float*)d_in[9], ws);
  qkv_f32v2<<<dim3(1536), dim3(256), 0, stream>>>(query, key, value, ws, b_q,
                                                  b_k, b_v, Qw, Kw, Vw);
  attn_kernel<<<dim3(32, 16, 2), dim3(256), 0, stream>>>(Qw, Kw, Vw, Aw);
  out_gemm64<<<dim3(512), dim3(256), 0, stream>>>(Aw, ws + 3145728, b_o,
                                                  (float*)d_out);
}

// Round 18
// 92.187 us; speedup vs baseline: 2.2901x; 1.1832x over previous
//
#include <hip/hip_runtime.h>

typedef unsigned short u16;
typedef u16 u16x8 __attribute__((ext_vector_type(8)));
typedef __bf16 bf16x8 __attribute__((ext_vector_type(8)));
typedef float f32x4 __attribute__((ext_vector_type(4)));

#define MFMA16 __builtin_amdgcn_mfma_f32_16x16x32_bf16

__device__ __forceinline__ u16 f2bf(float f) {
  unsigned u = __builtin_bit_cast(unsigned, f);
  u += 0x7FFFu + ((u >> 16) & 1u);
  return (u16)(u >> 16);
}

// XOR-swizzled LDS byte address for 64-bf16 (128B) rows (guide G4).
__device__ __forceinline__ int swz(int row, int bcol) {
  return row * 128 + (bcol ^ ((row & 7) << 4));
}

__device__ __forceinline__ void gl16(const u16* g, u16* l) {
  __builtin_amdgcn_global_load_lds(
      (const __attribute__((address_space(1))) unsigned int*)g,
      (__attribute__((address_space(3))) unsigned int*)l, 16, 0, 0);
}

// raw workgroup barrier (no forced vmcnt(0) drain)
__device__ __forceinline__ void BARR() {
  asm volatile("" ::: "memory");
  __builtin_amdgcn_s_barrier();
  asm volatile("" ::: "memory");
}
#define VMCNT(n) asm volatile("s_waitcnt vmcnt(" #n ")" ::: "memory")
#define LGKM0 asm volatile("s_waitcnt lgkmcnt(0)" ::: "memory")

// ---------------------------------------------------------------------------
// Flattened fp32 -> bf16 cast. 16M elements total, 8/thread, 8192 blocks.
// ws layout (u16): Wq 0 | Wk 1M | Wv 2M | Wo 3M | Xq 4M | Xk 8M | Xv 12M
// ---------------------------------------------------------------------------
__global__ __launch_bounds__(256)
void cast_all(const float* __restrict__ q, const float* __restrict__ k,
              const float* __restrict__ v, const float* __restrict__ wq,
              const float* __restrict__ wk, const float* __restrict__ wv,
              const float* __restrict__ wo, u16* __restrict__ ws) {
  const long i = ((long)blockIdx.x * 256 + threadIdx.x) * 8;
  const float* s;
  u16* d;
  if (i < 12582912) {  // X region (12M)
    const int seg = (int)(i >> 22);
    const float* xs = (seg == 0) ? q : (seg == 1) ? k : v;
    s = xs + (i & 4194303);
    d = ws + 4194304 + i;
  } else {  // weights (4M)
    const long j = i - 12582912;
    const int seg = (int)(j >> 20);
    const float* wsrc = (seg == 0) ? wq : (seg == 1) ? wk : (seg == 2) ? wv : wo;
    s = wsrc + (j & 1048575);
    d = ws + j;
  }
  float4 v0 = *(const float4*)s;
  float4 v1 = *(const float4*)(s + 4);
  u16x8 p = {f2bf(v0.x), f2bf(v0.y), f2bf(v0.z), f2bf(v0.w),
             f2bf(v1.x), f2bf(v1.y), f2bf(v1.z), f2bf(v1.w)};
  *(u16x8*)d = p;
}

// ---------------------------------------------------------------------------
// Shared 128x64-tile 2-phase counted-vmcnt GEMM core (r12-proven).
// 48 KB LDS -> 3 blocks/CU resident; 4 waves (2m x 2n), per-wave C = 64x32,
// 16 MFMA/K-tile. Phases split by N (A read ONLY in ph1, so ph2's A[t+2]
// staging into the same buf is 1 barrier past A's last read):
//  ph1: STG B[t+1] (2 gl16) | dsr A(8)+B-n0(2) | 8 MFMA (m x n0) | bar
//  ph2: STG A[t+2] (4 gl16) | dsr B-n1(2)      | 8 MFMA (m x n1) | vmcnt(4) | bar
// vmcnt(4): leaves A[t+2] (4 newest) in flight; retires A[t+1]+B[t+1].
// Tail: t=14 -> vmcnt(0); t=15 no stage/wait.
// Prologue: A0(4), B0(2), A1(4); vmcnt(4) retires A0+B0.
// ---------------------------------------------------------------------------
#define ZSTGA(tt, j)                                                        \
  gl16(Ain + (m0 + (w << 5) + (j)*8 + (lane >> 3)) * 1024 + (tt)*64 +       \
           (((lane & 7) ^ (lane >> 3)) << 3),                               \
       (u16*)(sb + ((tt)&1) * 24576 + (w << 12) + ((j) << 10)))
#define ZSTGB(tt, j)                                                        \
  gl16(W + (n0 + (w << 4) + (j)*8 + (lane >> 3)) * 1024 + (tt)*64 +         \
           (((lane & 7) ^ (lane >> 3)) << 3),                               \
       (u16*)(sb + ((tt)&1) * 24576 + 16384 + (w << 11) + ((j) << 10)))
#define ZLDA()                                                              \
  _Pragma("unroll") for (int m = 0; m < 4; ++m) {                           \
    char* p = sb + bo + rowAb + m * 2048;                                   \
    af[0][m] = __builtin_bit_cast(bf16x8, *(const u16x8*)(p + colr0));      \
    af[1][m] = __builtin_bit_cast(bf16x8, *(const u16x8*)(p + colr1));      \
  }
#define ZLDB(n)                                                             \
  {                                                                         \
    char* p = sb + bo + rowBb + (n)*2048;                                   \
    bf[0][n] = __builtin_bit_cast(bf16x8, *(const u16x8*)(p + colr0));      \
    bf[1][n] = __builtin_bit_cast(bf16x8, *(const u16x8*)(p + colr1));      \
  }
#define ZFMA(n)                                                             \
  __builtin_amdgcn_s_setprio(1);                                            \
  _Pragma("unroll") for (int m = 0; m < 4; ++m) {                           \
    acc[m][n] = MFMA16(af[0][m], bf[0][n], acc[m][n], 0, 0, 0);             \
    acc[m][n] = MFMA16(af[1][m], bf[1][n], acc[m][n], 0, 0, 0);             \
  }                                                                         \
  __builtin_amdgcn_s_setprio(0);

__device__ __forceinline__ void core64(const u16* __restrict__ Ain,
                                       const u16* __restrict__ W, int m0,
                                       int n0, char* sb, f32x4 (&acc)[4][2]) {
  const int tid = threadIdx.x, lane = tid & 63, w = tid >> 6;
  const int wm = w >> 1, wn = w & 1;
  const int r = lane & 15, g = lane >> 4;
  bf16x8 af[2][4], bf[2][2];

  const int colr0 = (g * 16) ^ ((r & 7) << 4);
  const int colr1 = (64 + g * 16) ^ ((r & 7) << 4);
  const int rowAb = (wm * 64 + r) * 128;
  const int rowBb = 16384 + (wn * 32 + r) * 128;

  // prologue: A0(4), B0(2), A1(4); A1 stays in flight
#pragma unroll
  for (int j = 0; j < 4; ++j) ZSTGA(0, j);
#pragma unroll
  for (int j = 0; j < 2; ++j) ZSTGB(0, j);
#pragma unroll
  for (int j = 0; j < 4; ++j) ZSTGA(1, j);
  VMCNT(4);
  __builtin_amdgcn_s_barrier();
  asm volatile("" ::: "memory");

  for (int t = 0; t < 16; ++t) {
    const int bo = (t & 1) * 24576;
    // ---- phase 1: all A + B-n0
    if (t < 15) { ZSTGB(t + 1, 0); ZSTGB(t + 1, 1); }
    ZLDA();
    ZLDB(0);
    ZFMA(0);
    BARR();
    // ---- phase 2: B-n1 only (A region not read -> A[t+2] staging safe)
    if (t < 14) { ZSTGA(t + 2, 0); ZSTGA(t + 2, 1); ZSTGA(t + 2, 2); ZSTGA(t + 2, 3); }
    ZLDB(1);
    ZFMA(1);
    if (t < 14) { VMCNT(4); } else if (t == 14) { VMCNT(0); }
    BARR();
  }
}

// ---------------------------------------------------------------------------
// QKV projection: 1536 blocks (3 z * 32 m * 16 n), 128x64 tile, 3 blocks/CU
// resident (2 full-residency rounds). Same core as out projection.
// ---------------------------------------------------------------------------
__global__ __launch_bounds__(256)
void qkv_gemm64(const u16* __restrict__ ws_in, const float* __restrict__ c0,
                const float* __restrict__ c1, const float* __restrict__ c2,
                u16* __restrict__ o0, u16* __restrict__ o1,
                u16* __restrict__ o2) {
  const int bid = blockIdx.x;
  const int s = (bid & 7) * 192 + (bid >> 3);  // XCD swizzle, 1536 % 8 == 0
  const int z = s / 512;
  const int rem = s & 511;
  const int m0 = (rem >> 4) << 7;  // 32 m-tiles of 128
  const int n0 = (rem & 15) << 6;  // 16 n-tiles of 64

  const u16* __restrict__ Ain = ws_in + 4194304 + z * 4194304;
  const u16* __restrict__ W = ws_in + z * 1048576;
  const float* Bi = (z == 0) ? c0 : (z == 1) ? c1 : c2;
  u16* O = (z == 0) ? o0 : (z == 1) ? o1 : o2;

  const int tid = threadIdx.x, lane = tid & 63, w = tid >> 6;
  const int wm = w >> 1, wn = w & 1;
  const int r = lane & 15, g = lane >> 4;

  __shared__ u16 SH[24576];  // 48 KB
  f32x4 acc[4][2] = {};
  core64(Ain, W, m0, n0, (char*)SH, acc);

  // epilogue -> bf16 [B,H,S,64]; C/D layout col=lane&15, row=g*4+q
#pragma unroll
  for (int n = 0; n < 2; ++n) {
    const int gn = n0 + wn * 32 + n * 16 + r;
    const int hh = gn >> 6, d = gn & 63;
    const float bv = Bi[gn];
#pragma unroll
    for (int m = 0; m < 4; ++m) {
#pragma unroll
      for (int q = 0; q < 4; ++q) {
        int gm = m0 + wm * 64 + m * 16 + g * 4 + q;
        int bb = gm >> 11, sIdx = gm & 2047;
        O[((bb * 16 + hh) * 2048 + sIdx) * 64 + d] = f2bf(acc[m][n][q] + bv);
      }
    }
  }
}

// ---------------------------------------------------------------------------
// Output projection: 512 blocks (32 m * 16 n), 128x64 tile, fp32 out.
// ---------------------------------------------------------------------------
__global__ __launch_bounds__(256)
void out_gemm64(const u16* __restrict__ Ain, const u16* __restrict__ W,
                const float* __restrict__ Bi, float* __restrict__ C) {
  const int bid = blockIdx.x;
  const int s = (bid & 7) * 64 + (bid >> 3);  // XCD swizzle, 512 % 8 == 0
  const int m0 = (s >> 4) << 7;  // 32 m-tiles of 128
  const int n0 = (s & 15) << 6;  // 16 n-tiles of 64

  const int tid = threadIdx.x, lane = tid & 63, w = tid >> 6;
  const int wm = w >> 1, wn = w & 1;
  const int r = lane & 15, g = lane >> 4;

  __shared__ u16 SH[24576];  // 48 KB
  f32x4 acc[4][2] = {};
  core64(Ain, W, m0, n0, (char*)SH, acc);

  // epilogue: fp32 C + bias
#pragma unroll
  for (int m = 0; m < 4; ++m) {
#pragma unroll
    for (int n = 0; n < 2; ++n) {
      int gn = n0 + wn * 32 + n * 16 + r;
      float bv = Bi[gn];
#pragma unroll
      for (int q = 0; q < 4; ++q) {
        int gm = m0 + wm * 64 + m * 16 + g * 4 + q;
        C[gm * 1024 + gn] = acc[m][n][q] + bv;
      }
    }
  }
}

// ---------------------------------------------------------------------------
// Sparse flash attention (r8 version, T14 async-stage + dbuf K/V), with
// T1 XCD-aware block swizzle: linear grid 1024; s=(bid&7)*128+(bid>>3)
// (bijective). Each XCD gets 4 (b,h) K/V panel groups x all 32 q-tiles ->
// K/V (1 MB) resident in that XCD's 4 MB L2.
// ---------------------------------------------------------------------------
__global__ __launch_bounds__(256)
void attn_kernel(const u16* __restrict__ Q, const u16* __restrict__ K,
                 const u16* __restrict__ V, u16* __restrict__ O) {
  const int bid = blockIdx.x;
  const int s_ = (bid & 7) * 128 + (bid >> 3);  // XCD swizzle, 1024 % 8 == 0
  const int qt = s_ & 31, h = (s_ >> 5) & 15, b = s_ >> 9;
  const int tid = threadIdx.x, lane = tid & 63, w = tid >> 6;
  const int r = lane & 15, g = lane >> 4;
  const int q0 = qt * 64;
  const int base = (b * 16 + h) * 131072;
  const u16* Qb = Q + base;

  __shared__ u16 Ks[2][4096];
  __shared__ u16 Vt[2][4096];  // transposed: Vt[d][j]
  __shared__ u16 Pl[4608];     // 4 waves x 16 rows x 144B stride

  bf16x8 qf[2];
  {
    const u16* qp = Qb + (q0 + w * 16 + r) * 64 + g * 8;
    qf[0] = __builtin_bit_cast(bf16x8, *(const u16x8*)qp);
    qf[1] = __builtin_bit_cast(bf16x8, *(const u16x8*)(qp + 32));
  }

  f32x4 acc[4] = {};
  float m_run[4] = {-1e30f, -1e30f, -1e30f, -1e30f};
  float l_run[4] = {};

  const int nt = (qt <= 3) ? (qt + 1) : 4;
  const int srow = tid >> 3, sc = (tid & 7) * 8;
  const u16* Kg = K + base + srow * 64 + sc;
  const u16* Vg = V + base + srow * 64 + sc;

  u16x8 krA[2], vrA[2], krB[2], vrB[2];
  krA[0] = *(const u16x8*)(Kg);
  krA[1] = *(const u16x8*)(Kg + 2048);
  vrA[0] = *(const u16x8*)(Vg);
  vrA[1] = *(const u16x8*)(Vg + 2048);

#pragma unroll
  for (int tix = 0; tix < 4; ++tix) {
    if (tix < nt) {
      const int j0 = ((tix == 0) ? 0 : ((qt <= 3) ? tix : (qt - 3 + tix))) * 64;
      const int bo = (tix & 1) * 8192;
      if ((tix & 1) == 0) {
#pragma unroll
        for (int i = 0; i < 2; ++i) {
          int row = i * 32 + srow;
          *(u16x8*)((char*)Ks + bo + swz(row, sc * 2)) = krA[i];
#pragma unroll
          for (int qq = 0; qq < 8; ++qq) {
            int d = sc + qq;
            *(u16*)((char*)Vt + bo + d * 128 + ((2 * row) ^ ((d & 7) << 4))) =
                vrA[i][qq];
          }
        }
      } else {
#pragma unroll
        for (int i = 0; i < 2; ++i) {
          int row = i * 32 + srow;
          *(u16x8*)((char*)Ks + bo + swz(row, sc * 2)) = krB[i];
#pragma unroll
          for (int qq = 0; qq < 8; ++qq) {
            int d = sc + qq;
            *(u16*)((char*)Vt + bo + d * 128 + ((2 * row) ^ ((d & 7) << 4))) =
                vrB[i][qq];
          }
        }
      }
      if (tix + 1 < nt) {
        const int jn = (((qt <= 3) ? (tix + 1) : (qt - 2 + tix)) * 64) * 64;
        if ((tix & 1) == 0) {
          krB[0] = *(const u16x8*)(Kg + jn);
          krB[1] = *(const u16x8*)(Kg + jn + 2048);
          vrB[0] = *(const u16x8*)(Vg + jn);
          vrB[1] = *(const u16x8*)(Vg + jn + 2048);
        } else {
          krA[0] = *(const u16x8*)(Kg + jn);
          krA[1] = *(const u16x8*)(Kg + jn + 2048);
          vrA[0] = *(const u16x8*)(Vg + jn);
          vrA[1] = *(const u16x8*)(Vg + jn + 2048);
        }
      }
      LGKM0;
      BARR();

      f32x4 S[4] = {};
#pragma unroll
      for (int kk = 0; kk < 2; ++kk)
#pragma unroll
        for (int n = 0; n < 4; ++n) {
          bf16x8 kf = __builtin_bit_cast(
              bf16x8, *(const u16x8*)((char*)Ks + bo +
                                      swz(n * 16 + r, kk * 64 + g * 16)));
          S[n] = MFMA16(qf[kk], kf, S[n], 0, 0, 0);
        }

      float mloc[4] = {-1e30f, -1e30f, -1e30f, -1e30f};
#pragma unroll
      for (int n = 0; n < 4; ++n) {
        int j = j0 + n * 16 + r;
#pragma unroll
        for (int q = 0; q < 4; ++q) {
          int i = q0 + w * 16 + g * 4 + q;
          bool ok = (j <= i) && (((i - j) <= 128) || (j < 16));
          float s = ok ? S[n][q] * 0.125f : -1e30f;
          S[n][q] = s;
          mloc[q] = fmaxf(mloc[q], s);
        }
      }
#pragma unroll
      for (int q = 0; q < 4; ++q)
#pragma unroll
        for (int off = 1; off < 16; off <<= 1)
          mloc[q] = fmaxf(mloc[q], __shfl_xor(mloc[q], off));

      float alpha[4], rsum[4] = {};
#pragma unroll
      for (int q = 0; q < 4; ++q) {
        float mn = fmaxf(m_run[q], mloc[q]);
        alpha[q] = __expf(m_run[q] - mn);
        m_run[q] = mn;
      }
#pragma unroll
      for (int n = 0; n < 4; ++n)
#pragma unroll
        for (int q = 0; q < 4; ++q) {
          float p = __expf(S[n][q] - m_run[q]);
          S[n][q] = p;
          rsum[q] += p;
        }
#pragma unroll
      for (int q = 0; q < 4; ++q) {
#pragma unroll
        for (int off = 1; off < 16; off <<= 1)
          rsum[q] += __shfl_xor(rsum[q], off);
        l_run[q] = l_run[q] * alpha[q] + rsum[q];
      }
#pragma unroll
      for (int n = 0; n < 4; ++n) {
        acc[n][0] *= alpha[0];
        acc[n][1] *= alpha[1];
        acc[n][2] *= alpha[2];
        acc[n][3] *= alpha[3];
      }

#pragma unroll
      for (int n = 0; n < 4; ++n)
#pragma unroll
        for (int q = 0; q < 4; ++q)
          *((u16*)((char*)Pl + w * 2304 + (g * 4 + q) * 144) + (n * 16 + r)) =
              f2bf(S[n][q]);

#pragma unroll
      for (int kk = 0; kk < 2; ++kk) {
        bf16x8 pf = __builtin_bit_cast(
            bf16x8, *(const u16x8*)((char*)Pl + w * 2304 + r * 144 + kk * 64 +
                                    g * 16));
#pragma unroll
        for (int n = 0; n < 4; ++n) {
          bf16x8 vf = __builtin_bit_cast(
              bf16x8, *(const u16x8*)((char*)Vt + bo +
                                      swz(n * 16 + r, kk * 64 + g * 16)));
          acc[n] = MFMA16(pf, vf, acc[n], 0, 0, 0);
        }
      }
    }
  }

#pragma unroll
  for (int n = 0; n < 4; ++n)
#pragma unroll
    for (int q = 0; q < 4; ++q) {
      int s = q0 + w * 16 + g * 4 + q;
      int d = n * 16 + r;
      O[(b * 2048 + s) * 1024 + h * 64 + d] = f2bf(acc[n][q] / l_run[q]);
    }
}

// ---------------------------------------------------------------------------
extern "C" void kernel_launch(void* const* d_in, const int* in_sizes, int n_in,
                              void* d_out, int out_size, void* d_ws,
                              size_t ws_size, hipStream_t stream) {
  const float* b_q = (const float*)d_in[4];
  const float* b_k = (const float*)d_in[6];
  const float* b_v = (const float*)d_in[8];
  const float* b_o = (const float*)d_in[10];

  u16* ws = (u16*)d_ws;
  // ws (u16): Wq 0 | Wk 1M | Wv 2M | Wo 3M | Xq 4M | Xk 8M | Xv 12M |
  //           Qw 16M | Kw 20M | Vw 24M | Aw aliases Xq (4M)
  u16* Qw = ws + 16777216;
  u16* Kw = ws + 20971520;
  u16* Vw = ws + 25165824;
  u16* Aw = ws + 4194304;  // aliases Xq (dead after qkv projection)

  cast_all<<<dim3(8192), dim3(256), 0, stream>>>(
      (const float*)d_in[0], (const float*)d_in[1], (const float*)d_in[2],
      (const float*)d_in[3], (const float*)d_in[5], (const float*)d_in[7],
      (const float*)d_in[9], ws);
  qkv_gemm64<<<dim3(1536), dim3(256), 0, stream>>>(ws, b_q, b_k, b_v, Qw, Kw,
                                                   Vw);
  attn_kernel<<<dim3(1024), dim3(256), 0, stream>>>(Qw, Kw, Vw, Aw);
  out_gemm64<<<dim3(512), dim3(256), 0, stream>>>(Aw, ws + 3145728, b_o,
                                                  (float*)d_out);
}

// Round 19
// 88.955 us; speedup vs baseline: 2.3733x; 1.0363x over previous
//
#include <hip/hip_runtime.h>

typedef unsigned short u16;
typedef u16 u16x8 __attribute__((ext_vector_type(8)));
typedef __bf16 bf16x8 __attribute__((ext_vector_type(8)));
typedef float f32x4 __attribute__((ext_vector_type(4)));

#define MFMA16 __builtin_amdgcn_mfma_f32_16x16x32_bf16

__device__ __forceinline__ u16 f2bf(float f) {
  unsigned u = __builtin_bit_cast(unsigned, f);
  u += 0x7FFFu + ((u >> 16) & 1u);
  return (u16)(u >> 16);
}

// XOR-swizzled LDS byte address for 64-bf16 (128B) rows (guide G4).
__device__ __forceinline__ int swz(int row, int bcol) {
  return row * 128 + (bcol ^ ((row & 7) << 4));
}

__device__ __forceinline__ void gl16(const u16* g, u16* l) {
  __builtin_amdgcn_global_load_lds(
      (const __attribute__((address_space(1))) unsigned int*)g,
      (__attribute__((address_space(3))) unsigned int*)l, 16, 0, 0);
}

// raw workgroup barrier (no forced vmcnt(0) drain)
__device__ __forceinline__ void BARR() {
  asm volatile("" ::: "memory");
  __builtin_amdgcn_s_barrier();
  asm volatile("" ::: "memory");
}
#define VMCNT(n) asm volatile("s_waitcnt vmcnt(" #n ")" ::: "memory")
#define LGKM0 asm volatile("s_waitcnt lgkmcnt(0)" ::: "memory")

// ---------------------------------------------------------------------------
// Flattened fp32 -> bf16 cast. 16M elements total, 8/thread, 8192 blocks.
// ws layout (u16): Wq 0 | Wk 1M | Wv 2M | Wo 3M | Xq 4M | Xk 8M | Xv 12M
// ---------------------------------------------------------------------------
__global__ __launch_bounds__(256)
void cast_all(const float* __restrict__ q, const float* __restrict__ k,
              const float* __restrict__ v, const float* __restrict__ wq,
              const float* __restrict__ wk, const float* __restrict__ wv,
              const float* __restrict__ wo, u16* __restrict__ ws) {
  const long i = ((long)blockIdx.x * 256 + threadIdx.x) * 8;
  const float* s;
  u16* d;
  if (i < 12582912) {  // X region (12M)
    const int seg = (int)(i >> 22);
    const float* xs = (seg == 0) ? q : (seg == 1) ? k : v;
    s = xs + (i & 4194303);
    d = ws + 4194304 + i;
  } else {  // weights (4M)
    const long j = i - 12582912;
    const int seg = (int)(j >> 20);
    const float* wsrc = (seg == 0) ? wq : (seg == 1) ? wk : (seg == 2) ? wv : wo;
    s = wsrc + (j & 1048575);
    d = ws + j;
  }
  float4 v0 = *(const float4*)s;
  float4 v1 = *(const float4*)(s + 4);
  u16x8 p = {f2bf(v0.x), f2bf(v0.y), f2bf(v0.z), f2bf(v0.w),
             f2bf(v1.x), f2bf(v1.y), f2bf(v1.z), f2bf(v1.w)};
  *(u16x8*)d = p;
}

// ---------------------------------------------------------------------------
// Shared 128x64-tile 2-phase counted-vmcnt GEMM core (r12-proven).
// 48 KB LDS -> 3 blocks/CU resident; 4 waves (2m x 2n), per-wave C = 64x32,
// 16 MFMA/K-tile. Phases split by N (A read ONLY in ph1, so ph2's A[t+2]
// staging into the same buf is 1 barrier past A's last read):
//  ph1: STG B[t+1] (2 gl16) | dsr A(8)+B-n0(2) | 8 MFMA (m x n0) | bar
//  ph2: STG A[t+2] (4 gl16) | dsr B-n1(2)      | 8 MFMA (m x n1) | vmcnt(4) | bar
// vmcnt(4): leaves A[t+2] (4 newest) in flight; retires A[t+1]+B[t+1].
// Tail: t=14 -> vmcnt(0); t=15 no stage/wait.
// Prologue: A0(4), B0(2), A1(4); vmcnt(4) retires A0+B0.
// ---------------------------------------------------------------------------
#define ZSTGA(tt, j)                                                        \
  gl16(Ain + (m0 + (w << 5) + (j)*8 + (lane >> 3)) * 1024 + (tt)*64 +       \
           (((lane & 7) ^ (lane >> 3)) << 3),                               \
       (u16*)(sb + ((tt)&1) * 24576 + (w << 12) + ((j) << 10)))
#define ZSTGB(tt, j)                                                        \
  gl16(W + (n0 + (w << 4) + (j)*8 + (lane >> 3)) * 1024 + (tt)*64 +         \
           (((lane & 7) ^ (lane >> 3)) << 3),                               \
       (u16*)(sb + ((tt)&1) * 24576 + 16384 + (w << 11) + ((j) << 10)))
#define ZLDA()                                                              \
  _Pragma("unroll") for (int m = 0; m < 4; ++m) {                           \
    char* p = sb + bo + rowAb + m * 2048;                                   \
    af[0][m] = __builtin_bit_cast(bf16x8, *(const u16x8*)(p + colr0));      \
    af[1][m] = __builtin_bit_cast(bf16x8, *(const u16x8*)(p + colr1));      \
  }
#define ZLDB(n)                                                             \
  {                                                                         \
    char* p = sb + bo + rowBb + (n)*2048;                                   \
    bf[0][n] = __builtin_bit_cast(bf16x8, *(const u16x8*)(p + colr0));      \
    bf[1][n] = __builtin_bit_cast(bf16x8, *(const u16x8*)(p + colr1));      \
  }
#define ZFMA(n)                                                             \
  __builtin_amdgcn_s_setprio(1);                                            \
  _Pragma("unroll") for (int m = 0; m < 4; ++m) {                           \
    acc[m][n] = MFMA16(af[0][m], bf[0][n], acc[m][n], 0, 0, 0);             \
    acc[m][n] = MFMA16(af[1][m], bf[1][n], acc[m][n], 0, 0, 0);             \
  }                                                                         \
  __builtin_amdgcn_s_setprio(0);

__device__ __forceinline__ void core64(const u16* __restrict__ Ain,
                                       const u16* __restrict__ W, int m0,
                                       int n0, char* sb, f32x4 (&acc)[4][2]) {
  const int tid = threadIdx.x, lane = tid & 63, w = tid >> 6;
  const int wm = w >> 1, wn = w & 1;
  const int r = lane & 15, g = lane >> 4;
  bf16x8 af[2][4], bf[2][2];

  const int colr0 = (g * 16) ^ ((r & 7) << 4);
  const int colr1 = (64 + g * 16) ^ ((r & 7) << 4);
  const int rowAb = (wm * 64 + r) * 128;
  const int rowBb = 16384 + (wn * 32 + r) * 128;

  // prologue: A0(4), B0(2), A1(4); A1 stays in flight
#pragma unroll
  for (int j = 0; j < 4; ++j) ZSTGA(0, j);
#pragma unroll
  for (int j = 0; j < 2; ++j) ZSTGB(0, j);
#pragma unroll
  for (int j = 0; j < 4; ++j) ZSTGA(1, j);
  VMCNT(4);
  __builtin_amdgcn_s_barrier();
  asm volatile("" ::: "memory");

  for (int t = 0; t < 16; ++t) {
    const int bo = (t & 1) * 24576;
    // ---- phase 1: all A + B-n0
    if (t < 15) { ZSTGB(t + 1, 0); ZSTGB(t + 1, 1); }
    ZLDA();
    ZLDB(0);
    ZFMA(0);
    BARR();
    // ---- phase 2: B-n1 only (A region not read -> A[t+2] staging safe)
    if (t < 14) { ZSTGA(t + 2, 0); ZSTGA(t + 2, 1); ZSTGA(t + 2, 2); ZSTGA(t + 2, 3); }
    ZLDB(1);
    ZFMA(1);
    if (t < 14) { VMCNT(4); } else if (t == 14) { VMCNT(0); }
    BARR();
  }
}

// ---------------------------------------------------------------------------
// QKV projection: 1536 blocks (3 z * 32 m * 16 n), 128x64 tile, 3 blocks/CU
// resident (2 full-residency rounds). Same core as out projection.
// ---------------------------------------------------------------------------
__global__ __launch_bounds__(256)
void qkv_gemm64(const u16* __restrict__ ws_in, const float* __restrict__ c0,
                const float* __restrict__ c1, const float* __restrict__ c2,
                u16* __restrict__ o0, u16* __restrict__ o1,
                u16* __restrict__ o2) {
  const int bid = blockIdx.x;
  const int s = (bid & 7) * 192 + (bid >> 3);  // XCD swizzle, 1536 % 8 == 0
  const int z = s / 512;
  const int rem = s & 511;
  const int m0 = (rem >> 4) << 7;  // 32 m-tiles of 128
  const int n0 = (rem & 15) << 6;  // 16 n-tiles of 64

  const u16* __restrict__ Ain = ws_in + 4194304 + z * 4194304;
  const u16* __restrict__ W = ws_in + z * 1048576;
  const float* Bi = (z == 0) ? c0 : (z == 1) ? c1 : c2;
  u16* O = (z == 0) ? o0 : (z == 1) ? o1 : o2;

  const int tid = threadIdx.x, lane = tid & 63, w = tid >> 6;
  const int wm = w >> 1, wn = w & 1;
  const int r = lane & 15, g = lane >> 4;

  __shared__ u16 SH[24576];  // 48 KB
  f32x4 acc[4][2] = {};
  core64(Ain, W, m0, n0, (char*)SH, acc);

  // epilogue -> bf16 [B,H,S,64]; C/D layout col=lane&15, row=g*4+q
#pragma unroll
  for (int n = 0; n < 2; ++n) {
    const int gn = n0 + wn * 32 + n * 16 + r;
    const int hh = gn >> 6, d = gn & 63;
    const float bv = Bi[gn];
#pragma unroll
    for (int m = 0; m < 4; ++m) {
#pragma unroll
      for (int q = 0; q < 4; ++q) {
        int gm = m0 + wm * 64 + m * 16 + g * 4 + q;
        int bb = gm >> 11, sIdx = gm & 2047;
        O[((bb * 16 + hh) * 2048 + sIdx) * 64 + d] = f2bf(acc[m][n][q] + bv);
      }
    }
  }
}

// ---------------------------------------------------------------------------
// Output projection: 512 blocks (32 m * 16 n), 128x64 tile, fp32 out.
// ---------------------------------------------------------------------------
__global__ __launch_bounds__(256)
void out_gemm64(const u16* __restrict__ Ain, const u16* __restrict__ W,
                const float* __restrict__ Bi, float* __restrict__ C) {
  const int bid = blockIdx.x;
  const int s = (bid & 7) * 64 + (bid >> 3);  // XCD swizzle, 512 % 8 == 0
  const int m0 = (s >> 4) << 7;  // 32 m-tiles of 128
  const int n0 = (s & 15) << 6;  // 16 n-tiles of 64

  const int tid = threadIdx.x, lane = tid & 63, w = tid >> 6;
  const int wm = w >> 1, wn = w & 1;
  const int r = lane & 15, g = lane >> 4;

  __shared__ u16 SH[24576];  // 48 KB
  f32x4 acc[4][2] = {};
  core64(Ain, W, m0, n0, (char*)SH, acc);

  // epilogue: fp32 C + bias
#pragma unroll
  for (int m = 0; m < 4; ++m) {
#pragma unroll
    for (int n = 0; n < 2; ++n) {
      int gn = n0 + wn * 32 + n * 16 + r;
      float bv = Bi[gn];
#pragma unroll
      for (int q = 0; q < 4; ++q) {
        int gm = m0 + wm * 64 + m * 16 + g * 4 + q;
        C[gm * 1024 + gn] = acc[m][n][q] + bv;
      }
    }
  }
}

// ---------------------------------------------------------------------------
// Sparse flash attention (r8 version, T14 async-stage + dbuf K/V).
// grid (32 qtiles, 16 heads, 2 batch), 256 threads (4 waves x 16 q-rows).
// ---------------------------------------------------------------------------
__global__ __launch_bounds__(256)
void attn_kernel(const u16* __restrict__ Q, const u16* __restrict__ K,
                 const u16* __restrict__ V, u16* __restrict__ O) {
  const int qt = blockIdx.x, h = blockIdx.y, b = blockIdx.z;
  const int tid = threadIdx.x, lane = tid & 63, w = tid >> 6;
  const int r = lane & 15, g = lane >> 4;
  const int q0 = qt * 64;
  const int base = (b * 16 + h) * 131072;
  const u16* Qb = Q + base;

  __shared__ u16 Ks[2][4096];
  __shared__ u16 Vt[2][4096];  // transposed: Vt[d][j]
  __shared__ u16 Pl[4608];     // 4 waves x 16 rows x 144B stride

  bf16x8 qf[2];
  {
    const u16* qp = Qb + (q0 + w * 16 + r) * 64 + g * 8;
    qf[0] = __builtin_bit_cast(bf16x8, *(const u16x8*)qp);
    qf[1] = __builtin_bit_cast(bf16x8, *(const u16x8*)(qp + 32));
  }

  f32x4 acc[4] = {};
  float m_run[4] = {-1e30f, -1e30f, -1e30f, -1e30f};
  float l_run[4] = {};

  const int nt = (qt <= 3) ? (qt + 1) : 4;
  const int srow = tid >> 3, sc = (tid & 7) * 8;
  const u16* Kg = K + base + srow * 64 + sc;
  const u16* Vg = V + base + srow * 64 + sc;

  u16x8 krA[2], vrA[2], krB[2], vrB[2];
  krA[0] = *(const u16x8*)(Kg);
  krA[1] = *(const u16x8*)(Kg + 2048);
  vrA[0] = *(const u16x8*)(Vg);
  vrA[1] = *(const u16x8*)(Vg + 2048);

#pragma unroll
  for (int tix = 0; tix < 4; ++tix) {
    if (tix < nt) {
      const int j0 = ((tix == 0) ? 0 : ((qt <= 3) ? tix : (qt - 3 + tix))) * 64;
      const int bo = (tix & 1) * 8192;
      if ((tix & 1) == 0) {
#pragma unroll
        for (int i = 0; i < 2; ++i) {
          int row = i * 32 + srow;
          *(u16x8*)((char*)Ks + bo + swz(row, sc * 2)) = krA[i];
#pragma unroll
          for (int qq = 0; qq < 8; ++qq) {
            int d = sc + qq;
            *(u16*)((char*)Vt + bo + d * 128 + ((2 * row) ^ ((d & 7) << 4))) =
                vrA[i][qq];
          }
        }
      } else {
#pragma unroll
        for (int i = 0; i < 2; ++i) {
          int row = i * 32 + srow;
          *(u16x8*)((char*)Ks + bo + swz(row, sc * 2)) = krB[i];
#pragma unroll
          for (int qq = 0; qq < 8; ++qq) {
            int d = sc + qq;
            *(u16*)((char*)Vt + bo + d * 128 + ((2 * row) ^ ((d & 7) << 4))) =
                vrB[i][qq];
          }
        }
      }
      if (tix + 1 < nt) {
        const int jn = (((qt <= 3) ? (tix + 1) : (qt - 2 + tix)) * 64) * 64;
        if ((tix & 1) == 0) {
          krB[0] = *(const u16x8*)(Kg + jn);
          krB[1] = *(const u16x8*)(Kg + jn + 2048);
          vrB[0] = *(const u16x8*)(Vg + jn);
          vrB[1] = *(const u16x8*)(Vg + jn + 2048);
        } else {
          krA[0] = *(const u16x8*)(Kg + jn);
          krA[1] = *(const u16x8*)(Kg + jn + 2048);
          vrA[0] = *(const u16x8*)(Vg + jn);
          vrA[1] = *(const u16x8*)(Vg + jn + 2048);
        }
      }
      LGKM0;
      BARR();

      f32x4 S[4] = {};
#pragma unroll
      for (int kk = 0; kk < 2; ++kk)
#pragma unroll
        for (int n = 0; n < 4; ++n) {
          bf16x8 kf = __builtin_bit_cast(
              bf16x8, *(const u16x8*)((char*)Ks + bo +
                                      swz(n * 16 + r, kk * 64 + g * 16)));
          S[n] = MFMA16(qf[kk], kf, S[n], 0, 0, 0);
        }

      float mloc[4] = {-1e30f, -1e30f, -1e30f, -1e30f};
#pragma unroll
      for (int n = 0; n < 4; ++n) {
        int j = j0 + n * 16 + r;
#pragma unroll
        for (int q = 0; q < 4; ++q) {
          int i = q0 + w * 16 + g * 4 + q;
          bool ok = (j <= i) && (((i - j) <= 128) || (j < 16));
          float s = ok ? S[n][q] * 0.125f : -1e30f;
          S[n][q] = s;
          mloc[q] = fmaxf(mloc[q], s);
        }
      }
#pragma unroll
      for (int q = 0; q < 4; ++q)
#pragma unroll
        for (int off = 1; off < 16; off <<= 1)
          mloc[q] = fmaxf(mloc[q], __shfl_xor(mloc[q], off));

      float alpha[4], rsum[4] = {};
#pragma unroll
      for (int q = 0; q < 4; ++q) {
        float mn = fmaxf(m_run[q], mloc[q]);
        alpha[q] = __expf(m_run[q] - mn);
        m_run[q] = mn;
      }
#pragma unroll
      for (int n = 0; n < 4; ++n)
#pragma unroll
        for (int q = 0; q < 4; ++q) {
          float p = __expf(S[n][q] - m_run[q]);
          S[n][q] = p;
          rsum[q] += p;
        }
#pragma unroll
      for (int q = 0; q < 4; ++q) {
#pragma unroll
        for (int off = 1; off < 16; off <<= 1)
          rsum[q] += __shfl_xor(rsum[q], off);
        l_run[q] = l_run[q] * alpha[q] + rsum[q];
      }
#pragma unroll
      for (int n = 0; n < 4; ++n) {
        acc[n][0] *= alpha[0];
        acc[n][1] *= alpha[1];
        acc[n][2] *= alpha[2];
        acc[n][3] *= alpha[3];
      }

#pragma unroll
      for (int n = 0; n < 4; ++n)
#pragma unroll
        for (int q = 0; q < 4; ++q)
          *((u16*)((char*)Pl + w * 2304 + (g * 4 + q) * 144) + (n * 16 + r)) =
              f2bf(S[n][q]);

#pragma unroll
      for (int kk = 0; kk < 2; ++kk) {
        bf16x8 pf = __builtin_bit_cast(
            bf16x8, *(const u16x8*)((char*)Pl + w * 2304 + r * 144 + kk * 64 +
                                    g * 16));
#pragma unroll
        for (int n = 0; n < 4; ++n) {
          bf16x8 vf = __builtin_bit_cast(
              bf16x8, *(const u16x8*)((char*)Vt + bo +
                                      swz(n * 16 + r, kk * 64 + g * 16)));
          acc[n] = MFMA16(pf, vf, acc[n], 0, 0, 0);
        }
      }
    }
  }

#pragma unroll
  for (int n = 0; n < 4; ++n)
#pragma unroll
    for (int q = 0; q < 4; ++q) {
      int s = q0 + w * 16 + g * 4 + q;
      int d = n * 16 + r;
      O[(b * 2048 + s) * 1024 + h * 64 + d] = f2bf(acc[n][q] / l_run[q]);
    }
}

// ---------------------------------------------------------------------------
extern "C" void kernel_launch(void* const* d_in, const int* in_sizes, int n_in,
                              void* d_out, int out_size, void* d_ws,
                              size_t ws_size, hipStream_t stream) {
  const float* b_q = (const float*)d_in[4];
  const float* b_k = (const float*)d_in[6];
  const float* b_v = (const float*)d_in[8];
  const float* b_o = (const float*)d_in[10];

  u16* ws = (u16*)d_ws;
  // ws (u16): Wq 0 | Wk 1M | Wv 2M | Wo 3M | Xq 4M | Xk 8M | Xv 12M |
  //           Qw 16M | Kw 20M | Vw 24M | Aw aliases Xq (4M)
  u16* Qw = ws + 16777216;
  u16* Kw = ws + 20971520;
  u16* Vw = ws + 25165824;
  u16* Aw = ws + 4194304;  // aliases Xq (dead after qkv projection)

  cast_all<<<dim3(8192), dim3(256), 0, stream>>>(
      (const float*)d_in[0], (const float*)d_in[1], (const float*)d_in[2],
      (const float*)d_in[3], (const float*)d_in[5], (const float*)d_in[7],
      (const float*)d_in[9], ws);
  qkv_gemm64<<<dim3(1536), dim3(256), 0, stream>>>(ws, b_q, b_k, b_v, Qw, Kw,
                                                   Vw);
  attn_kernel<<<dim3(32, 16, 2), dim3(256), 0, stream>>>(Qw, Kw, Vw, Aw);
  out_gemm64<<<dim3(512), dim3(256), 0, stream>>>(Aw, ws + 3145728, b_o,
                                                  (float*)d_out);
}